// Round 1
// baseline (349.195 us; speedup 1.0000x reference)
//
#include <hip/hip_runtime.h>
#include <hip/hip_bf16.h>

typedef __attribute__((ext_vector_type(8))) __bf16 bf16x8;
typedef __attribute__((ext_vector_type(4))) __bf16 bf16x4;
typedef __attribute__((ext_vector_type(4))) float f32x4;

#define SEQ 128
#define DIM 1024
#define BATCH 128
#define MTOT (BATCH * SEQ)   // 16384

// ---------------- cast f32 -> bf16, 8 elems/thread ----------------
__global__ void cast_f32_bf16(const float* __restrict__ in, __bf16* __restrict__ out, int n) {
    int i = (blockIdx.x * blockDim.x + threadIdx.x) * 8;
    if (i >= n) return;
    float4 f0 = *reinterpret_cast<const float4*>(in + i);
    float4 f1 = *reinterpret_cast<const float4*>(in + i + 4);
    bf16x8 o;
    o[0] = (__bf16)f0.x; o[1] = (__bf16)f0.y; o[2] = (__bf16)f0.z; o[3] = (__bf16)f0.w;
    o[4] = (__bf16)f1.x; o[5] = (__bf16)f1.y; o[6] = (__bf16)f1.z; o[7] = (__bf16)f1.w;
    *reinterpret_cast<bf16x8*>(out + i) = o;
}

// ---------------- GEMM: C[M][N] = A[M][K] * W[N][K]^T + bias[N] ----------------
// MODE 0: write bf16 row-major C[M][N]
// MODE 1: write f32 row-major C[M][N]
// MODE 2: write bf16 transposed per batch: C[b][n][s] with b = row/128, s = row%128
template <int MODE>
__global__ __launch_bounds__(256) void gemm_bt(const __bf16* __restrict__ A,
                                               const __bf16* __restrict__ W,
                                               const float* __restrict__ bias,
                                               void* __restrict__ Cout,
                                               int M, int N, int K) {
    __shared__ __bf16 Ash[128][40];  // BK=32, pad to 40 (+16B) -> conflict-free b128 reads
    __shared__ __bf16 Wsh[128][40];
    const int tid  = threadIdx.x;
    const int wave = tid >> 6, lane = tid & 63;
    const int wr = wave >> 1, wc = wave & 1;
    const int m0 = blockIdx.x * 128, n0 = blockIdx.y * 128;
    const int lr = lane & 15, lk = (lane >> 4) * 8;
    const int lrow = tid >> 2;        // 0..63
    const int lcol = (tid & 3) * 8;   // 0,8,16,24

    f32x4 acc[4][4] = {};

    for (int k0 = 0; k0 < K; k0 += 32) {
        __syncthreads();
        #pragma unroll
        for (int h = 0; h < 2; ++h) {
            int r = lrow + h * 64;
            *reinterpret_cast<bf16x8*>(&Ash[r][lcol]) =
                *reinterpret_cast<const bf16x8*>(&A[(size_t)(m0 + r) * K + k0 + lcol]);
            *reinterpret_cast<bf16x8*>(&Wsh[r][lcol]) =
                *reinterpret_cast<const bf16x8*>(&W[(size_t)(n0 + r) * K + k0 + lcol]);
        }
        __syncthreads();
        bf16x8 af[4], bfr[4];
        #pragma unroll
        for (int i = 0; i < 4; ++i) {
            af[i]  = *reinterpret_cast<const bf16x8*>(&Ash[wr * 64 + i * 16 + lr][lk]);
            bfr[i] = *reinterpret_cast<const bf16x8*>(&Wsh[wc * 64 + i * 16 + lr][lk]);
        }
        #pragma unroll
        for (int i = 0; i < 4; ++i)
            #pragma unroll
            for (int j = 0; j < 4; ++j)
                acc[i][j] = __builtin_amdgcn_mfma_f32_16x16x32_bf16(af[i], bfr[j], acc[i][j], 0, 0, 0);
    }

    const int rbase = (lane >> 4) * 4;
    #pragma unroll
    for (int i = 0; i < 4; ++i) {
        #pragma unroll
        for (int j = 0; j < 4; ++j) {
            const int gc  = n0 + wc * 64 + j * 16 + lr;
            const float bv = bias[gc];
            const int grb = m0 + wr * 64 + i * 16 + rbase;
            if (MODE == 0) {
                __bf16* C = (__bf16*)Cout;
                #pragma unroll
                for (int r = 0; r < 4; ++r)
                    C[(size_t)(grb + r) * N + gc] = (__bf16)(acc[i][j][r] + bv);
            } else if (MODE == 1) {
                float* C = (float*)Cout;
                #pragma unroll
                for (int r = 0; r < 4; ++r)
                    C[(size_t)(grb + r) * N + gc] = acc[i][j][r] + bv;
            } else {
                __bf16* C = (__bf16*)Cout;
                const int b = grb >> 7, s = grb & 127;
                bf16x4 v;
                #pragma unroll
                for (int r = 0; r < 4; ++r) v[r] = (__bf16)(acc[i][j][r] + bv);
                *reinterpret_cast<bf16x4*>(&C[((size_t)b * DIM + gc) * SEQ + s]) = v;
            }
        }
    }
}

// ---------------- fused attention per batch ----------------
// S = softmax(Q K^T / sqrt(D)); att = S V  (V given transposed: Vt[b][e][s])
__global__ __launch_bounds__(256) void attn_kernel(const __bf16* __restrict__ Q,
                                                   const __bf16* __restrict__ Km,
                                                   const __bf16* __restrict__ Vt,
                                                   __bf16* __restrict__ Ab) {
    __shared__ float Ssh[128][129];
    const int b = blockIdx.x;
    const int tid = threadIdx.x, wave = tid >> 6, lane = tid & 63;
    const int lr = lane & 15, lk = (lane >> 4) * 8, rbase = (lane >> 4) * 4;
    const __bf16* Qb = Q  + (size_t)b * SEQ * DIM;
    const __bf16* Kb = Km + (size_t)b * SEQ * DIM;
    const __bf16* Vb = Vt + (size_t)b * DIM * SEQ;

    // phase 1: scores for rows [32*wave, 32*wave+32)
    f32x4 acc[2][8] = {};
    for (int k0 = 0; k0 < DIM; k0 += 32) {
        bf16x8 qf[2];
        #pragma unroll
        for (int i = 0; i < 2; ++i)
            qf[i] = *reinterpret_cast<const bf16x8*>(&Qb[(size_t)(wave * 32 + i * 16 + lr) * DIM + k0 + lk]);
        #pragma unroll
        for (int j = 0; j < 8; ++j) {
            bf16x8 kf = *reinterpret_cast<const bf16x8*>(&Kb[(size_t)(j * 16 + lr) * DIM + k0 + lk]);
            #pragma unroll
            for (int i = 0; i < 2; ++i)
                acc[i][j] = __builtin_amdgcn_mfma_f32_16x16x32_bf16(qf[i], kf, acc[i][j], 0, 0, 0);
        }
    }
    const float scale = 0.03125f;  // 1/sqrt(1024)
    #pragma unroll
    for (int i = 0; i < 2; ++i)
        #pragma unroll
        for (int j = 0; j < 8; ++j)
            #pragma unroll
            for (int r = 0; r < 4; ++r)
                Ssh[wave * 32 + i * 16 + rbase + r][j * 16 + lr] = acc[i][j][r] * scale;
    __syncthreads();

    // softmax: one thread per row
    if (tid < 128) {
        float m = -1e30f;
        for (int j = 0; j < 128; ++j) m = fmaxf(m, Ssh[tid][j]);
        float s = 0.f;
        for (int j = 0; j < 128; ++j) { float e = __expf(Ssh[tid][j] - m); Ssh[tid][j] = e; s += e; }
        float inv = 1.f / s;
        for (int j = 0; j < 128; ++j) Ssh[tid][j] *= inv;
    }
    __syncthreads();

    // phase 2: att = P V ; A-frags (P) hoisted, B-frags from Vt contiguous
    bf16x8 pf[2][4];
    #pragma unroll
    for (int i = 0; i < 2; ++i)
        #pragma unroll
        for (int ks = 0; ks < 4; ++ks) {
            bf16x8 v;
            #pragma unroll
            for (int e = 0; e < 8; ++e)
                v[e] = (__bf16)Ssh[wave * 32 + i * 16 + lr][ks * 32 + lk + e];
            pf[i][ks] = v;
        }
    __bf16* Ao = Ab + (size_t)b * SEQ * DIM;
    for (int n0 = 0; n0 < DIM; n0 += 16) {
        f32x4 a2[2] = {};
        #pragma unroll
        for (int ks = 0; ks < 4; ++ks) {
            bf16x8 vf = *reinterpret_cast<const bf16x8*>(&Vb[(size_t)(n0 + lr) * SEQ + ks * 32 + lk]);
            #pragma unroll
            for (int i = 0; i < 2; ++i)
                a2[i] = __builtin_amdgcn_mfma_f32_16x16x32_bf16(pf[i][ks], vf, a2[i], 0, 0, 0);
        }
        #pragma unroll
        for (int i = 0; i < 2; ++i)
            #pragma unroll
            for (int r = 0; r < 4; ++r)
                Ao[(size_t)(wave * 32 + i * 16 + rbase + r) * DIM + n0 + lr] = (__bf16)a2[i][r];
    }
}

extern "C" void kernel_launch(void* const* d_in, const int* in_sizes, int n_in,
                              void* d_out, int out_size, void* d_ws, size_t ws_size,
                              hipStream_t stream) {
    const float* x  = (const float*)d_in[0];
    const float* Wq = (const float*)d_in[1];
    const float* bq = (const float*)d_in[2];
    const float* Wk = (const float*)d_in[3];
    const float* bk = (const float*)d_in[4];
    const float* Wv = (const float*)d_in[5];
    const float* bv = (const float*)d_in[6];
    const float* Wo = (const float*)d_in[7];
    const float* bo = (const float*)d_in[8];

    char* ws = (char*)d_ws;
    const size_t MB = 1024 * 1024;
    __bf16* Xb  = (__bf16*)(ws);              // 32MB; reused as Ab after V GEMM
    __bf16* Wqb = (__bf16*)(ws + 32 * MB);    // 2MB
    __bf16* Wkb = (__bf16*)(ws + 34 * MB);
    __bf16* Wvb = (__bf16*)(ws + 36 * MB);
    __bf16* Wob = (__bf16*)(ws + 38 * MB);
    __bf16* Qb  = (__bf16*)(ws + 40 * MB);    // 32MB
    __bf16* Kb  = (__bf16*)(ws + 72 * MB);    // 32MB
    __bf16* Vt  = (__bf16*)(ws + 104 * MB);   // 32MB
    __bf16* Ab  = Xb;

    const int nX = MTOT * DIM;   // 16,777,216
    const int nW = DIM * DIM;    // 1,048,576
    cast_f32_bf16<<<nX / 8 / 256, 256, 0, stream>>>(x, Xb, nX);
    cast_f32_bf16<<<nW / 8 / 256, 256, 0, stream>>>(Wq, Wqb, nW);
    cast_f32_bf16<<<nW / 8 / 256, 256, 0, stream>>>(Wk, Wkb, nW);
    cast_f32_bf16<<<nW / 8 / 256, 256, 0, stream>>>(Wv, Wvb, nW);
    cast_f32_bf16<<<nW / 8 / 256, 256, 0, stream>>>(Wo, Wob, nW);

    dim3 ggrid(MTOT / 128, DIM / 128);
    gemm_bt<0><<<ggrid, 256, 0, stream>>>(Xb, Wqb, bq, (void*)Qb, MTOT, DIM, DIM);
    gemm_bt<0><<<ggrid, 256, 0, stream>>>(Xb, Wkb, bk, (void*)Kb, MTOT, DIM, DIM);
    gemm_bt<2><<<ggrid, 256, 0, stream>>>(Xb, Wvb, bv, (void*)Vt, MTOT, DIM, DIM);

    attn_kernel<<<BATCH, 256, 0, stream>>>(Qb, Kb, Vt, Ab);

    gemm_bt<1><<<ggrid, 256, 0, stream>>>(Ab, Wob, bo, d_out, MTOT, DIM, DIM);
}

// Round 2
// 303.701 us; speedup vs baseline: 1.1498x; 1.1498x over previous
//
#include <hip/hip_runtime.h>
#include <hip/hip_bf16.h>

typedef __attribute__((ext_vector_type(8))) __bf16 bf16x8;
typedef __attribute__((ext_vector_type(4))) __bf16 bf16x4;
typedef __attribute__((ext_vector_type(4))) float f32x4;

#define SEQ 128
#define DIM 1024
#define BATCH 128
#define MTOT (BATCH * SEQ)   // 16384

// async global -> LDS, 16B per lane (global_load_lds_dwordx4)
__device__ __forceinline__ void gload16(const void* g, void* l) {
    __builtin_amdgcn_global_load_lds(
        (const __attribute__((address_space(1))) void*)g,
        (__attribute__((address_space(3))) void*)l, 16, 0, 0);
}

// ---------------- cast f32 -> bf16, 8 elems/thread ----------------
__global__ void cast_f32_bf16(const float* __restrict__ in, __bf16* __restrict__ out, int n) {
    int i = (blockIdx.x * blockDim.x + threadIdx.x) * 8;
    if (i >= n) return;
    float4 f0 = *reinterpret_cast<const float4*>(in + i);
    float4 f1 = *reinterpret_cast<const float4*>(in + i + 4);
    bf16x8 o;
    o[0] = (__bf16)f0.x; o[1] = (__bf16)f0.y; o[2] = (__bf16)f0.z; o[3] = (__bf16)f0.w;
    o[4] = (__bf16)f1.x; o[5] = (__bf16)f1.y; o[6] = (__bf16)f1.z; o[7] = (__bf16)f1.w;
    *reinterpret_cast<bf16x8*>(out + i) = o;
}

// ---------------- GEMM: C[M][N] = A[M][K] * W[N][K]^T + bias[N] ----------------
// m97 structure: linear LDS [128][32] bf16, global_load_lds width 16, 2-barrier K-loop.
// MODE 0: bf16 row-major; MODE 1: f32 row-major; MODE 2: bf16 transposed per batch C[b][n][s]
template <int MODE>
__global__ __launch_bounds__(256) void gemm_bt(const __bf16* __restrict__ A,
                                               const __bf16* __restrict__ W,
                                               const float* __restrict__ bias,
                                               void* __restrict__ Cout,
                                               int M, int N, int K) {
    __shared__ __bf16 Ash[128 * 32];
    __shared__ __bf16 Wsh[128 * 32];
    const int tid  = threadIdx.x;
    const int wave = tid >> 6, lane = tid & 63;
    const int wr = wave >> 1, wc = wave & 1;
    const int m0 = blockIdx.x * 128, n0 = blockIdx.y * 128;
    const int lr = lane & 15, lk = (lane >> 4) * 8;
    // staging: per wave-issue 1KB = 16 rows x 64B; lane -> row lane/4, colbyte (lane%4)*16
    const int srow = wave * 16 + (lane >> 2);  // 0..63 within half
    const int scol = (lane & 3) * 8;

    f32x4 acc[4][4] = {};

    for (int k0 = 0; k0 < K; k0 += 32) {
        __syncthreads();  // previous iter's frag reads done before overwrite
        #pragma unroll
        for (int h = 0; h < 2; ++h) {
            gload16(&A[(size_t)(m0 + h * 64 + srow) * K + k0 + scol], &Ash[(h * 64 + wave * 16) * 32]);
            gload16(&W[(size_t)(n0 + h * 64 + srow) * K + k0 + scol], &Wsh[(h * 64 + wave * 16) * 32]);
        }
        __syncthreads();  // compiler drains vmcnt(0) before barrier -> tiles ready
        bf16x8 af[4], bfr[4];
        #pragma unroll
        for (int i = 0; i < 4; ++i) {
            af[i]  = *reinterpret_cast<const bf16x8*>(&Ash[(wr * 64 + i * 16 + lr) * 32 + lk]);
            bfr[i] = *reinterpret_cast<const bf16x8*>(&Wsh[(wc * 64 + i * 16 + lr) * 32 + lk]);
        }
        #pragma unroll
        for (int i = 0; i < 4; ++i)
            #pragma unroll
            for (int j = 0; j < 4; ++j)
                acc[i][j] = __builtin_amdgcn_mfma_f32_16x16x32_bf16(af[i], bfr[j], acc[i][j], 0, 0, 0);
    }

    const int rbase = (lane >> 4) * 4;
    #pragma unroll
    for (int i = 0; i < 4; ++i) {
        #pragma unroll
        for (int j = 0; j < 4; ++j) {
            const int gc  = n0 + wc * 64 + j * 16 + lr;
            const float bv = bias[gc];
            const int grb = m0 + wr * 64 + i * 16 + rbase;
            if (MODE == 0) {
                __bf16* C = (__bf16*)Cout;
                #pragma unroll
                for (int r = 0; r < 4; ++r)
                    C[(size_t)(grb + r) * N + gc] = (__bf16)(acc[i][j][r] + bv);
            } else if (MODE == 1) {
                float* C = (float*)Cout;
                #pragma unroll
                for (int r = 0; r < 4; ++r)
                    C[(size_t)(grb + r) * N + gc] = acc[i][j][r] + bv;
            } else {
                __bf16* C = (__bf16*)Cout;
                const int b = grb >> 7, s = grb & 127;
                bf16x4 v;
                #pragma unroll
                for (int r = 0; r < 4; ++r) v[r] = (__bf16)(acc[i][j][r] + bv);
                *reinterpret_cast<bf16x4*>(&C[((size_t)b * DIM + gc) * SEQ + s]) = v;
            }
        }
    }
}

// ---------------- fused attention ----------------
// Grid: 512 blocks (XCD-swizzled so 4 same-batch blocks share an XCD L2).
// Each block: one (batch, 32-row tile). 4 waves.
__global__ __launch_bounds__(256) void attn_kernel(const __bf16* __restrict__ Q,
                                                   const __bf16* __restrict__ Km,
                                                   const __bf16* __restrict__ Vt,
                                                   __bf16* __restrict__ Ab) {
    __shared__ float  Ssh[32][132];
    __shared__ __bf16 Psh[32][136];
    const int bid = blockIdx.x;
    const int logical = (bid & 7) * 64 + (bid >> 3);  // XCD x -> batches [16x,16x+16)
    const int b = logical >> 2, rt = logical & 3;
    const int tid = threadIdx.x, wave = tid >> 6, lane = tid & 63;
    const int lr = lane & 15, lk = (lane >> 4) * 8, rbase = (lane >> 4) * 4;
    const __bf16* Qb = Q  + ((size_t)b * SEQ + rt * 32) * DIM;
    const __bf16* Kb = Km + (size_t)b * SEQ * DIM;
    const __bf16* Vb = Vt + (size_t)b * DIM * SEQ;

    // phase 1: scores for 32 rows; wave w covers key-cols [32w, 32w+32)
    f32x4 acc[2][2] = {};
    for (int k0 = 0; k0 < DIM; k0 += 32) {
        bf16x8 qf[2], kf[2];
        #pragma unroll
        for (int i = 0; i < 2; ++i)
            qf[i] = *reinterpret_cast<const bf16x8*>(&Qb[(size_t)(i * 16 + lr) * DIM + k0 + lk]);
        #pragma unroll
        for (int j = 0; j < 2; ++j)
            kf[j] = *reinterpret_cast<const bf16x8*>(&Kb[(size_t)(wave * 32 + j * 16 + lr) * DIM + k0 + lk]);
        #pragma unroll
        for (int i = 0; i < 2; ++i)
            #pragma unroll
            for (int j = 0; j < 2; ++j)
                acc[i][j] = __builtin_amdgcn_mfma_f32_16x16x32_bf16(qf[i], kf[j], acc[i][j], 0, 0, 0);
    }
    const float scale = 0.03125f;  // 1/sqrt(1024)
    #pragma unroll
    for (int i = 0; i < 2; ++i)
        #pragma unroll
        for (int j = 0; j < 2; ++j)
            #pragma unroll
            for (int r = 0; r < 4; ++r)
                Ssh[i * 16 + rbase + r][wave * 32 + j * 16 + lr] = acc[i][j][r] * scale;
    __syncthreads();

    // wave-parallel softmax: 8 threads per row, 16 elems per thread, shfl_xor reduce
    {
        const int row = tid >> 3;
        const int c0  = (tid & 7) * 16;
        float4 v0 = *reinterpret_cast<const float4*>(&Ssh[row][c0]);
        float4 v1 = *reinterpret_cast<const float4*>(&Ssh[row][c0 + 4]);
        float4 v2 = *reinterpret_cast<const float4*>(&Ssh[row][c0 + 8]);
        float4 v3 = *reinterpret_cast<const float4*>(&Ssh[row][c0 + 12]);
        float e[16] = {v0.x, v0.y, v0.z, v0.w, v1.x, v1.y, v1.z, v1.w,
                       v2.x, v2.y, v2.z, v2.w, v3.x, v3.y, v3.z, v3.w};
        float mx = e[0];
        #pragma unroll
        for (int u = 1; u < 16; ++u) mx = fmaxf(mx, e[u]);
        mx = fmaxf(mx, __shfl_xor(mx, 1));
        mx = fmaxf(mx, __shfl_xor(mx, 2));
        mx = fmaxf(mx, __shfl_xor(mx, 4));
        float s = 0.f;
        #pragma unroll
        for (int u = 0; u < 16; ++u) { e[u] = __expf(e[u] - mx); s += e[u]; }
        s += __shfl_xor(s, 1);
        s += __shfl_xor(s, 2);
        s += __shfl_xor(s, 4);
        const float inv = 1.f / s;
        bf16x8 p0, p1;
        #pragma unroll
        for (int u = 0; u < 8; ++u) { p0[u] = (__bf16)(e[u] * inv); p1[u] = (__bf16)(e[u + 8] * inv); }
        *reinterpret_cast<bf16x8*>(&Psh[row][c0])     = p0;
        *reinterpret_cast<bf16x8*>(&Psh[row][c0 + 8]) = p1;
    }
    __syncthreads();

    // phase 2: att = P V; wave w covers embed-cols [256w, 256w+256)
    bf16x8 pf[2][4];
    #pragma unroll
    for (int i = 0; i < 2; ++i)
        #pragma unroll
        for (int ks = 0; ks < 4; ++ks)
            pf[i][ks] = *reinterpret_cast<const bf16x8*>(&Psh[i * 16 + lr][ks * 32 + lk]);
    __bf16* Ao = Ab + ((size_t)b * SEQ + rt * 32) * DIM;
    for (int n0 = wave * 256; n0 < wave * 256 + 256; n0 += 16) {
        f32x4 a2[2] = {};
        #pragma unroll
        for (int ks = 0; ks < 4; ++ks) {
            bf16x8 vf = *reinterpret_cast<const bf16x8*>(&Vb[(size_t)(n0 + lr) * SEQ + ks * 32 + lk]);
            #pragma unroll
            for (int i = 0; i < 2; ++i)
                a2[i] = __builtin_amdgcn_mfma_f32_16x16x32_bf16(pf[i][ks], vf, a2[i], 0, 0, 0);
        }
        #pragma unroll
        for (int i = 0; i < 2; ++i)
            #pragma unroll
            for (int r = 0; r < 4; ++r)
                Ao[(size_t)(i * 16 + rbase + r) * DIM + n0 + lr] = (__bf16)a2[i][r];
    }
}

extern "C" void kernel_launch(void* const* d_in, const int* in_sizes, int n_in,
                              void* d_out, int out_size, void* d_ws, size_t ws_size,
                              hipStream_t stream) {
    const float* x  = (const float*)d_in[0];
    const float* Wq = (const float*)d_in[1];
    const float* bq = (const float*)d_in[2];
    const float* Wk = (const float*)d_in[3];
    const float* bk = (const float*)d_in[4];
    const float* Wv = (const float*)d_in[5];
    const float* bv = (const float*)d_in[6];
    const float* Wo = (const float*)d_in[7];
    const float* bo = (const float*)d_in[8];

    char* ws = (char*)d_ws;
    const size_t MB = 1024 * 1024;
    __bf16* Xb  = (__bf16*)(ws);              // 32MB; reused as Ab after attention
    __bf16* Wqb = (__bf16*)(ws + 32 * MB);    // 2MB each
    __bf16* Wkb = (__bf16*)(ws + 34 * MB);
    __bf16* Wvb = (__bf16*)(ws + 36 * MB);
    __bf16* Wob = (__bf16*)(ws + 38 * MB);
    __bf16* Qb  = (__bf16*)(ws + 40 * MB);    // 32MB
    __bf16* Kb  = (__bf16*)(ws + 72 * MB);    // 32MB
    __bf16* Vt  = (__bf16*)(ws + 104 * MB);   // 32MB
    __bf16* Ab  = Xb;

    const int nX = MTOT * DIM;
    const int nW = DIM * DIM;
    cast_f32_bf16<<<nX / 8 / 256, 256, 0, stream>>>(x, Xb, nX);
    cast_f32_bf16<<<nW / 8 / 256, 256, 0, stream>>>(Wq, Wqb, nW);
    cast_f32_bf16<<<nW / 8 / 256, 256, 0, stream>>>(Wk, Wkb, nW);
    cast_f32_bf16<<<nW / 8 / 256, 256, 0, stream>>>(Wv, Wvb, nW);
    cast_f32_bf16<<<nW / 8 / 256, 256, 0, stream>>>(Wo, Wob, nW);

    dim3 ggrid(MTOT / 128, DIM / 128);
    gemm_bt<0><<<ggrid, 256, 0, stream>>>(Xb, Wqb, bq, (void*)Qb, MTOT, DIM, DIM);
    gemm_bt<0><<<ggrid, 256, 0, stream>>>(Xb, Wkb, bk, (void*)Kb, MTOT, DIM, DIM);
    gemm_bt<2><<<ggrid, 256, 0, stream>>>(Xb, Wvb, bv, (void*)Vt, MTOT, DIM, DIM);

    attn_kernel<<<512, 256, 0, stream>>>(Qb, Kb, Vt, Ab);

    gemm_bt<1><<<ggrid, 256, 0, stream>>>(Ab, Wob, bo, d_out, MTOT, DIM, DIM);
}

// Round 3
// 224.988 us; speedup vs baseline: 1.5521x; 1.3499x over previous
//
#include <hip/hip_runtime.h>
#include <hip/hip_bf16.h>

typedef __attribute__((ext_vector_type(8))) __bf16 bf16x8;
typedef __attribute__((ext_vector_type(4))) __bf16 bf16x4;
typedef __attribute__((ext_vector_type(4))) float f32x4;

#define SEQ 128
#define DIM 1024
#define BATCH 128
#define MTOT (BATCH * SEQ)   // 16384

// async global -> LDS, 16B per lane (global_load_lds_dwordx4)
__device__ __forceinline__ void gload16(const void* g, void* l) {
    __builtin_amdgcn_global_load_lds(
        (const __attribute__((address_space(1))) void*)g,
        (__attribute__((address_space(3))) void*)l, 16, 0, 0);
}

#define BARRIER() do { asm volatile("" ::: "memory"); __builtin_amdgcn_s_barrier(); asm volatile("" ::: "memory"); } while (0)
#define WAITV4() asm volatile("s_waitcnt vmcnt(4)" ::: "memory")
#define WAITV0() asm volatile("s_waitcnt vmcnt(0)" ::: "memory")
#define MFMA(a, b, c) __builtin_amdgcn_mfma_f32_16x16x32_bf16(a, b, c, 0, 0, 0)

// ---------------- cast f32 -> bf16, 8 elems/thread ----------------
__global__ void cast_f32_bf16(const float* __restrict__ in, __bf16* __restrict__ out, int n) {
    int i = (blockIdx.x * blockDim.x + threadIdx.x) * 8;
    if (i >= n) return;
    float4 f0 = *reinterpret_cast<const float4*>(in + i);
    float4 f1 = *reinterpret_cast<const float4*>(in + i + 4);
    bf16x8 o;
    o[0] = (__bf16)f0.x; o[1] = (__bf16)f0.y; o[2] = (__bf16)f0.z; o[3] = (__bf16)f0.w;
    o[4] = (__bf16)f1.x; o[5] = (__bf16)f1.y; o[6] = (__bf16)f1.z; o[7] = (__bf16)f1.w;
    *reinterpret_cast<bf16x8*>(out + i) = o;
}

// ---------------- GEMM 256x256 tile, 8 waves, 3-buffer pipelined, counted vmcnt ----------------
// C[M][N] = A[M][K] * W[N][K]^T + bias[N];  M=16384, N=K=1024 fixed.
// MODE 0: bf16 row-major; MODE 1: f32 row-major; MODE 2: bf16 per-batch transposed C[b][n][s]
// LDS frag-read swizzle: byte cb ^= ((r>>1)&3)<<4 (2-way max = free). Staging writes linear LDS
// with inverse-swizzled per-lane GLOBAL source (rule: both-sides-or-neither with global_load_lds).
template <int MODE>
__global__ __launch_bounds__(512, 1) void gemm256(const __bf16* __restrict__ A,
                                                  const __bf16* __restrict__ W,
                                                  const float* __restrict__ bias,
                                                  void* __restrict__ Cout) {
    const int K = 1024, N = 1024;
    __shared__ __bf16 lds[3][4][4096];   // 96KB: [buf][A0,A1,B0,B1][128 rows x 32 k]
    const int tid = threadIdx.x, wave = tid >> 6, lane = tid & 63;
    const int wr = wave >> 2, wc = wave & 3;          // 2x4 wave grid; wave tile 128x64
    const int lr = lane & 15;
    const int lkb = ((lane >> 4) & 3) * 16;           // frag k-offset in bytes
    // XCD swizzle: 256 blocks, 8 XCDs -> 32 consecutive logical ids per XCD
    const int bid = blockIdx.x;
    const int swz = (bid & 7) * 32 + (bid >> 3);
    const int m0 = (swz >> 2) * 256, n0 = (swz & 3) * 256;
    // staging geometry: wave stages 1KB per half-slot; lane covers 16B
    const int rloc = wave * 16 + (lane >> 2);                              // row 0..127
    const int cbs  = ((((lane & 3) << 4) ^ (((lane >> 3) & 3) << 4)) >> 1); // src col elem (inv-swz)
    const __bf16* pA = A + (size_t)(m0 + rloc) * K + cbs;
    const __bf16* pB = W + (size_t)(n0 + rloc) * K + cbs;
    const int wo = wave * 512;

    f32x4 acc[8][4] = {};

// swizzled LDS fragment read (16B)
#define LDF(SLOT, R) (*reinterpret_cast<const bf16x8*>( \
        reinterpret_cast<const char*>(SLOT) + (R) * 64 + (lkb ^ ((((R) >> 1) & 3) << 4))))
#define STAGE_A(SB, TS) do { gload16(pA + (TS) * 32, &lds[SB][0][wo]); \
                             gload16(pA + (size_t)128 * 1024 + (TS) * 32, &lds[SB][1][wo]); } while (0)
#define STAGE_B(SB, TS) do { gload16(pB + (TS) * 32, &lds[SB][2][wo]); \
                             gload16(pB + (size_t)128 * 1024 + (TS) * 32, &lds[SB][3][wo]); } while (0)

// One K-tile (BK=32): 2 phases x {ds_read, stage, barrier, 16 MFMA, barrier}
#define TILE(RB, SB, TS, DOSTAGE, VMSTMT) do { \
    const __bf16* As_ = &lds[RB][wr][0]; \
    const __bf16* Bs_ = &lds[RB][2 + (wc >> 1)][0]; \
    const int bb_ = (wc & 1) * 64; \
    bf16x8 a0 = LDF(As_, 0 * 16 + lr), a1 = LDF(As_, 1 * 16 + lr); \
    bf16x8 a2 = LDF(As_, 2 * 16 + lr), a3 = LDF(As_, 3 * 16 + lr); \
    bf16x8 b0 = LDF(Bs_, bb_ + 0 * 16 + lr), b1 = LDF(Bs_, bb_ + 1 * 16 + lr); \
    bf16x8 b2 = LDF(Bs_, bb_ + 2 * 16 + lr), b3 = LDF(Bs_, bb_ + 3 * 16 + lr); \
    if (DOSTAGE) STAGE_A(SB, TS); \
    BARRIER(); \
    __builtin_amdgcn_s_setprio(1); \
    acc[0][0] = MFMA(a0, b0, acc[0][0]); acc[0][1] = MFMA(a0, b1, acc[0][1]); \
    acc[0][2] = MFMA(a0, b2, acc[0][2]); acc[0][3] = MFMA(a0, b3, acc[0][3]); \
    acc[1][0] = MFMA(a1, b0, acc[1][0]); acc[1][1] = MFMA(a1, b1, acc[1][1]); \
    acc[1][2] = MFMA(a1, b2, acc[1][2]); acc[1][3] = MFMA(a1, b3, acc[1][3]); \
    acc[2][0] = MFMA(a2, b0, acc[2][0]); acc[2][1] = MFMA(a2, b1, acc[2][1]); \
    acc[2][2] = MFMA(a2, b2, acc[2][2]); acc[2][3] = MFMA(a2, b3, acc[2][3]); \
    acc[3][0] = MFMA(a3, b0, acc[3][0]); acc[3][1] = MFMA(a3, b1, acc[3][1]); \
    acc[3][2] = MFMA(a3, b2, acc[3][2]); acc[3][3] = MFMA(a3, b3, acc[3][3]); \
    __builtin_amdgcn_s_setprio(0); \
    BARRIER(); \
    a0 = LDF(As_, 4 * 16 + lr); a1 = LDF(As_, 5 * 16 + lr); \
    a2 = LDF(As_, 6 * 16 + lr); a3 = LDF(As_, 7 * 16 + lr); \
    if (DOSTAGE) STAGE_B(SB, TS); \
    BARRIER(); \
    __builtin_amdgcn_s_setprio(1); \
    acc[4][0] = MFMA(a0, b0, acc[4][0]); acc[4][1] = MFMA(a0, b1, acc[4][1]); \
    acc[4][2] = MFMA(a0, b2, acc[4][2]); acc[4][3] = MFMA(a0, b3, acc[4][3]); \
    acc[5][0] = MFMA(a1, b0, acc[5][0]); acc[5][1] = MFMA(a1, b1, acc[5][1]); \
    acc[5][2] = MFMA(a1, b2, acc[5][2]); acc[5][3] = MFMA(a1, b3, acc[5][3]); \
    acc[6][0] = MFMA(a2, b0, acc[6][0]); acc[6][1] = MFMA(a2, b1, acc[6][1]); \
    acc[6][2] = MFMA(a2, b2, acc[6][2]); acc[6][3] = MFMA(a2, b3, acc[6][3]); \
    acc[7][0] = MFMA(a3, b0, acc[7][0]); acc[7][1] = MFMA(a3, b1, acc[7][1]); \
    acc[7][2] = MFMA(a3, b2, acc[7][2]); acc[7][3] = MFMA(a3, b3, acc[7][3]); \
    __builtin_amdgcn_s_setprio(0); \
    VMSTMT; \
    BARRIER(); \
} while (0)

    // prologue: stage tiles 0 (buf0) and 1 (buf1); counted wait -> tile 0 landed
    STAGE_A(0, 0); STAGE_B(0, 0);
    STAGE_A(1, 1); STAGE_B(1, 1);
    WAITV4();
    BARRIER();

    // main loop: 30 staged tiles (bufs rotate 0,1,2); tile t stages tile t+2 into buf (t+2)%3
    for (int it = 0; it < 10; ++it) {
        const int t = it * 3;
        TILE(0, 2, t + 2, 1, WAITV4());
        TILE(1, 0, t + 3, 1, WAITV4());
        TILE(2, 1, t + 4, 1, WAITV4());
    }
    TILE(0, 0, 0, 0, WAITV0());   // tile 30: drain remaining (tile 31's) loads
    TILE(1, 0, 0, 0, (void)0);    // tile 31

    // epilogue
    const int rbase = (lane >> 4) * 4;
    #pragma unroll
    for (int ri = 0; ri < 8; ++ri) {
        #pragma unroll
        for (int j = 0; j < 4; ++j) {
            const int gc  = n0 + wc * 64 + j * 16 + lr;
            const float bv = bias[gc];
            const int grb = m0 + wr * 128 + ri * 16 + rbase;
            if (MODE == 0) {
                __bf16* C = (__bf16*)Cout;
                #pragma unroll
                for (int r = 0; r < 4; ++r)
                    C[(size_t)(grb + r) * N + gc] = (__bf16)(acc[ri][j][r] + bv);
            } else if (MODE == 1) {
                float* C = (float*)Cout;
                #pragma unroll
                for (int r = 0; r < 4; ++r)
                    C[(size_t)(grb + r) * N + gc] = acc[ri][j][r] + bv;
            } else {
                __bf16* C = (__bf16*)Cout;
                const int b = grb >> 7, s = grb & 127;
                bf16x4 v;
                #pragma unroll
                for (int r = 0; r < 4; ++r) v[r] = (__bf16)(acc[ri][j][r] + bv);
                *reinterpret_cast<bf16x4*>(&C[((size_t)b * DIM + gc) * SEQ + s]) = v;
            }
        }
    }
#undef TILE
#undef STAGE_A
#undef STAGE_B
#undef LDF
}

// ---------------- fused attention ----------------
// Grid: 512 blocks (XCD-swizzled). Each block: one (batch, 32-row tile). 4 waves.
__global__ __launch_bounds__(256) void attn_kernel(const __bf16* __restrict__ Q,
                                                   const __bf16* __restrict__ Km,
                                                   const __bf16* __restrict__ Vt,
                                                   __bf16* __restrict__ Ab) {
    __shared__ float  Ssh[32][132];
    __shared__ __bf16 Psh[32][136];
    const int bid = blockIdx.x;
    const int logical = (bid & 7) * 64 + (bid >> 3);  // XCD x -> batches [16x,16x+16)
    const int b = logical >> 2, rt = logical & 3;
    const int tid = threadIdx.x, wave = tid >> 6, lane = tid & 63;
    const int lr = lane & 15, lk = (lane >> 4) * 8, rbase = (lane >> 4) * 4;
    const __bf16* Qb = Q  + ((size_t)b * SEQ + rt * 32) * DIM;
    const __bf16* Kb = Km + (size_t)b * SEQ * DIM;
    const __bf16* Vb = Vt + (size_t)b * DIM * SEQ;

    // phase 1: scores for 32 rows; wave w covers key-cols [32w, 32w+32)
    f32x4 acc[2][2] = {};
    for (int k0 = 0; k0 < DIM; k0 += 32) {
        bf16x8 qf[2], kf[2];
        #pragma unroll
        for (int i = 0; i < 2; ++i)
            qf[i] = *reinterpret_cast<const bf16x8*>(&Qb[(size_t)(i * 16 + lr) * DIM + k0 + lk]);
        #pragma unroll
        for (int j = 0; j < 2; ++j)
            kf[j] = *reinterpret_cast<const bf16x8*>(&Kb[(size_t)(wave * 32 + j * 16 + lr) * DIM + k0 + lk]);
        #pragma unroll
        for (int i = 0; i < 2; ++i)
            #pragma unroll
            for (int j = 0; j < 2; ++j)
                acc[i][j] = MFMA(qf[i], kf[j], acc[i][j]);
    }
    const float scale = 0.03125f;  // 1/sqrt(1024)
    #pragma unroll
    for (int i = 0; i < 2; ++i)
        #pragma unroll
        for (int j = 0; j < 2; ++j)
            #pragma unroll
            for (int r = 0; r < 4; ++r)
                Ssh[i * 16 + rbase + r][wave * 32 + j * 16 + lr] = acc[i][j][r] * scale;
    __syncthreads();

    // wave-parallel softmax: 8 threads per row, shfl_xor reduce
    {
        const int row = tid >> 3;
        const int c0  = (tid & 7) * 16;
        float4 v0 = *reinterpret_cast<const float4*>(&Ssh[row][c0]);
        float4 v1 = *reinterpret_cast<const float4*>(&Ssh[row][c0 + 4]);
        float4 v2 = *reinterpret_cast<const float4*>(&Ssh[row][c0 + 8]);
        float4 v3 = *reinterpret_cast<const float4*>(&Ssh[row][c0 + 12]);
        float e[16] = {v0.x, v0.y, v0.z, v0.w, v1.x, v1.y, v1.z, v1.w,
                       v2.x, v2.y, v2.z, v2.w, v3.x, v3.y, v3.z, v3.w};
        float mx = e[0];
        #pragma unroll
        for (int u = 1; u < 16; ++u) mx = fmaxf(mx, e[u]);
        mx = fmaxf(mx, __shfl_xor(mx, 1));
        mx = fmaxf(mx, __shfl_xor(mx, 2));
        mx = fmaxf(mx, __shfl_xor(mx, 4));
        float s = 0.f;
        #pragma unroll
        for (int u = 0; u < 16; ++u) { e[u] = __expf(e[u] - mx); s += e[u]; }
        s += __shfl_xor(s, 1);
        s += __shfl_xor(s, 2);
        s += __shfl_xor(s, 4);
        const float inv = 1.f / s;
        bf16x8 p0, p1;
        #pragma unroll
        for (int u = 0; u < 8; ++u) { p0[u] = (__bf16)(e[u] * inv); p1[u] = (__bf16)(e[u + 8] * inv); }
        *reinterpret_cast<bf16x8*>(&Psh[row][c0])     = p0;
        *reinterpret_cast<bf16x8*>(&Psh[row][c0 + 8]) = p1;
    }
    __syncthreads();

    // phase 2: att = P V; wave w covers embed-cols [256w, 256w+256)
    bf16x8 pf[2][4];
    #pragma unroll
    for (int i = 0; i < 2; ++i)
        #pragma unroll
        for (int ks = 0; ks < 4; ++ks)
            pf[i][ks] = *reinterpret_cast<const bf16x8*>(&Psh[i * 16 + lr][ks * 32 + lk]);
    __bf16* Ao = Ab + ((size_t)b * SEQ + rt * 32) * DIM;
    for (int n0 = wave * 256; n0 < wave * 256 + 256; n0 += 16) {
        f32x4 a2[2] = {};
        #pragma unroll
        for (int ks = 0; ks < 4; ++ks) {
            bf16x8 vf = *reinterpret_cast<const bf16x8*>(&Vb[(size_t)(n0 + lr) * SEQ + ks * 32 + lk]);
            #pragma unroll
            for (int i = 0; i < 2; ++i)
                a2[i] = MFMA(pf[i][ks], vf, a2[i]);
        }
        #pragma unroll
        for (int i = 0; i < 2; ++i)
            #pragma unroll
            for (int r = 0; r < 4; ++r)
                Ao[(size_t)(i * 16 + rbase + r) * DIM + n0 + lr] = (__bf16)a2[i][r];
    }
}

extern "C" void kernel_launch(void* const* d_in, const int* in_sizes, int n_in,
                              void* d_out, int out_size, void* d_ws, size_t ws_size,
                              hipStream_t stream) {
    const float* x  = (const float*)d_in[0];
    const float* Wq = (const float*)d_in[1];
    const float* bq = (const float*)d_in[2];
    const float* Wk = (const float*)d_in[3];
    const float* bk = (const float*)d_in[4];
    const float* Wv = (const float*)d_in[5];
    const float* bv = (const float*)d_in[6];
    const float* Wo = (const float*)d_in[7];
    const float* bo = (const float*)d_in[8];

    char* ws = (char*)d_ws;
    const size_t MB = 1024 * 1024;
    __bf16* Xb  = (__bf16*)(ws);              // 32MB; reused as Ab after attention
    __bf16* Wqb = (__bf16*)(ws + 32 * MB);    // 2MB each
    __bf16* Wkb = (__bf16*)(ws + 34 * MB);
    __bf16* Wvb = (__bf16*)(ws + 36 * MB);
    __bf16* Wob = (__bf16*)(ws + 38 * MB);
    __bf16* Qb  = (__bf16*)(ws + 40 * MB);    // 32MB
    __bf16* Kb  = (__bf16*)(ws + 72 * MB);    // 32MB
    __bf16* Vt  = (__bf16*)(ws + 104 * MB);   // 32MB
    __bf16* Ab  = Xb;

    const int nX = MTOT * DIM;
    const int nW = DIM * DIM;
    cast_f32_bf16<<<nX / 8 / 256, 256, 0, stream>>>(x, Xb, nX);
    cast_f32_bf16<<<nW / 8 / 256, 256, 0, stream>>>(Wq, Wqb, nW);
    cast_f32_bf16<<<nW / 8 / 256, 256, 0, stream>>>(Wk, Wkb, nW);
    cast_f32_bf16<<<nW / 8 / 256, 256, 0, stream>>>(Wv, Wvb, nW);
    cast_f32_bf16<<<nW / 8 / 256, 256, 0, stream>>>(Wo, Wob, nW);

    gemm256<0><<<256, 512, 0, stream>>>(Xb, Wqb, bq, (void*)Qb);
    gemm256<0><<<256, 512, 0, stream>>>(Xb, Wkb, bk, (void*)Kb);
    gemm256<2><<<256, 512, 0, stream>>>(Xb, Wvb, bv, (void*)Vt);

    attn_kernel<<<512, 256, 0, stream>>>(Qb, Kb, Vt, Ab);

    gemm256<1><<<256, 512, 0, stream>>>(Ab, Wob, bo, d_out);
}

// Round 4
// 199.728 us; speedup vs baseline: 1.7484x; 1.1265x over previous
//
#include <hip/hip_runtime.h>
#include <hip/hip_bf16.h>

typedef __attribute__((ext_vector_type(8))) __bf16 bf16x8;
typedef __attribute__((ext_vector_type(4))) __bf16 bf16x4;
typedef __attribute__((ext_vector_type(4))) float f32x4;

#define SEQ 128
#define DIM 1024
#define BATCH 128
#define MTOT (BATCH * SEQ)   // 16384

// async global -> LDS, 16B per lane (global_load_lds_dwordx4)
__device__ __forceinline__ void gload16(const void* g, void* l) {
    __builtin_amdgcn_global_load_lds(
        (const __attribute__((address_space(1))) void*)g,
        (__attribute__((address_space(3))) void*)l, 16, 0, 0);
}

#define BARRIER() do { asm volatile("" ::: "memory"); __builtin_amdgcn_s_barrier(); asm volatile("" ::: "memory"); } while (0)
#define WAITV(N) asm volatile("s_waitcnt vmcnt(" #N ")" ::: "memory")
#define MFMA(a, b, c) __builtin_amdgcn_mfma_f32_16x16x32_bf16(a, b, c, 0, 0, 0)

// ---------------- cast f32 -> bf16, 8 elems/thread ----------------
__global__ void cast_f32_bf16(const float* __restrict__ in, __bf16* __restrict__ out, int n) {
    int i = (blockIdx.x * blockDim.x + threadIdx.x) * 8;
    if (i >= n) return;
    float4 f0 = *reinterpret_cast<const float4*>(in + i);
    float4 f1 = *reinterpret_cast<const float4*>(in + i + 4);
    bf16x8 o;
    o[0] = (__bf16)f0.x; o[1] = (__bf16)f0.y; o[2] = (__bf16)f0.z; o[3] = (__bf16)f0.w;
    o[4] = (__bf16)f1.x; o[5] = (__bf16)f1.y; o[6] = (__bf16)f1.z; o[7] = (__bf16)f1.w;
    *reinterpret_cast<bf16x8*>(out + i) = o;
}

// ---------------- GEMM 256x256 tile, 8 waves, 3-buffer pipelined, counted vmcnt ----------------
// (unchanged from round 3: ~1040 TF)
template <int MODE>
__global__ __launch_bounds__(512, 1) void gemm256(const __bf16* __restrict__ A,
                                                  const __bf16* __restrict__ W,
                                                  const float* __restrict__ bias,
                                                  void* __restrict__ Cout) {
    const int K = 1024, N = 1024;
    __shared__ __bf16 lds[3][4][4096];   // 96KB
    const int tid = threadIdx.x, wave = tid >> 6, lane = tid & 63;
    const int wr = wave >> 2, wc = wave & 3;
    const int lr = lane & 15;
    const int lkb = ((lane >> 4) & 3) * 16;
    const int bid = blockIdx.x;
    const int swz = (bid & 7) * 32 + (bid >> 3);
    const int m0 = (swz >> 2) * 256, n0 = (swz & 3) * 256;
    const int rloc = wave * 16 + (lane >> 2);
    const int cbs  = ((((lane & 3) << 4) ^ (((lane >> 3) & 3) << 4)) >> 1);
    const __bf16* pA = A + (size_t)(m0 + rloc) * K + cbs;
    const __bf16* pB = W + (size_t)(n0 + rloc) * K + cbs;
    const int wo = wave * 512;

    f32x4 acc[8][4] = {};

#define LDF(SLOT, R) (*reinterpret_cast<const bf16x8*>( \
        reinterpret_cast<const char*>(SLOT) + (R) * 64 + (lkb ^ ((((R) >> 1) & 3) << 4))))
#define STAGE_A(SB, TS) do { gload16(pA + (TS) * 32, &lds[SB][0][wo]); \
                             gload16(pA + (size_t)128 * 1024 + (TS) * 32, &lds[SB][1][wo]); } while (0)
#define STAGE_B(SB, TS) do { gload16(pB + (TS) * 32, &lds[SB][2][wo]); \
                             gload16(pB + (size_t)128 * 1024 + (TS) * 32, &lds[SB][3][wo]); } while (0)

#define TILE(RB, SB, TS, DOSTAGE, VMSTMT) do { \
    const __bf16* As_ = &lds[RB][wr][0]; \
    const __bf16* Bs_ = &lds[RB][2 + (wc >> 1)][0]; \
    const int bb_ = (wc & 1) * 64; \
    bf16x8 a0 = LDF(As_, 0 * 16 + lr), a1 = LDF(As_, 1 * 16 + lr); \
    bf16x8 a2 = LDF(As_, 2 * 16 + lr), a3 = LDF(As_, 3 * 16 + lr); \
    bf16x8 b0 = LDF(Bs_, bb_ + 0 * 16 + lr), b1 = LDF(Bs_, bb_ + 1 * 16 + lr); \
    bf16x8 b2 = LDF(Bs_, bb_ + 2 * 16 + lr), b3 = LDF(Bs_, bb_ + 3 * 16 + lr); \
    if (DOSTAGE) STAGE_A(SB, TS); \
    BARRIER(); \
    __builtin_amdgcn_s_setprio(1); \
    acc[0][0] = MFMA(a0, b0, acc[0][0]); acc[0][1] = MFMA(a0, b1, acc[0][1]); \
    acc[0][2] = MFMA(a0, b2, acc[0][2]); acc[0][3] = MFMA(a0, b3, acc[0][3]); \
    acc[1][0] = MFMA(a1, b0, acc[1][0]); acc[1][1] = MFMA(a1, b1, acc[1][1]); \
    acc[1][2] = MFMA(a1, b2, acc[1][2]); acc[1][3] = MFMA(a1, b3, acc[1][3]); \
    acc[2][0] = MFMA(a2, b0, acc[2][0]); acc[2][1] = MFMA(a2, b1, acc[2][1]); \
    acc[2][2] = MFMA(a2, b2, acc[2][2]); acc[2][3] = MFMA(a2, b3, acc[2][3]); \
    acc[3][0] = MFMA(a3, b0, acc[3][0]); acc[3][1] = MFMA(a3, b1, acc[3][1]); \
    acc[3][2] = MFMA(a3, b2, acc[3][2]); acc[3][3] = MFMA(a3, b3, acc[3][3]); \
    __builtin_amdgcn_s_setprio(0); \
    BARRIER(); \
    a0 = LDF(As_, 4 * 16 + lr); a1 = LDF(As_, 5 * 16 + lr); \
    a2 = LDF(As_, 6 * 16 + lr); a3 = LDF(As_, 7 * 16 + lr); \
    if (DOSTAGE) STAGE_B(SB, TS); \
    BARRIER(); \
    __builtin_amdgcn_s_setprio(1); \
    acc[4][0] = MFMA(a0, b0, acc[4][0]); acc[4][1] = MFMA(a0, b1, acc[4][1]); \
    acc[4][2] = MFMA(a0, b2, acc[4][2]); acc[4][3] = MFMA(a0, b3, acc[4][3]); \
    acc[5][0] = MFMA(a1, b0, acc[5][0]); acc[5][1] = MFMA(a1, b1, acc[5][1]); \
    acc[5][2] = MFMA(a1, b2, acc[5][2]); acc[5][3] = MFMA(a1, b3, acc[5][3]); \
    acc[6][0] = MFMA(a2, b0, acc[6][0]); acc[6][1] = MFMA(a2, b1, acc[6][1]); \
    acc[6][2] = MFMA(a2, b2, acc[6][2]); acc[6][3] = MFMA(a2, b3, acc[6][3]); \
    acc[7][0] = MFMA(a3, b0, acc[7][0]); acc[7][1] = MFMA(a3, b1, acc[7][1]); \
    acc[7][2] = MFMA(a3, b2, acc[7][2]); acc[7][3] = MFMA(a3, b3, acc[7][3]); \
    __builtin_amdgcn_s_setprio(0); \
    VMSTMT; \
    BARRIER(); \
} while (0)

    STAGE_A(0, 0); STAGE_B(0, 0);
    STAGE_A(1, 1); STAGE_B(1, 1);
    WAITV(4);
    BARRIER();

    for (int it = 0; it < 10; ++it) {
        const int t = it * 3;
        TILE(0, 2, t + 2, 1, WAITV(4));
        TILE(1, 0, t + 3, 1, WAITV(4));
        TILE(2, 1, t + 4, 1, WAITV(4));
    }
    TILE(0, 0, 0, 0, WAITV(0));
    TILE(1, 0, 0, 0, (void)0);

    const int rbase = (lane >> 4) * 4;
    #pragma unroll
    for (int ri = 0; ri < 8; ++ri) {
        #pragma unroll
        for (int j = 0; j < 4; ++j) {
            const int gc  = n0 + wc * 64 + j * 16 + lr;
            const float bv = bias[gc];
            const int grb = m0 + wr * 128 + ri * 16 + rbase;
            if (MODE == 0) {
                __bf16* C = (__bf16*)Cout;
                #pragma unroll
                for (int r = 0; r < 4; ++r)
                    C[(size_t)(grb + r) * N + gc] = (__bf16)(acc[ri][j][r] + bv);
            } else if (MODE == 1) {
                float* C = (float*)Cout;
                #pragma unroll
                for (int r = 0; r < 4; ++r)
                    C[(size_t)(grb + r) * N + gc] = acc[ri][j][r] + bv;
            } else {
                __bf16* C = (__bf16*)Cout;
                const int b = grb >> 7, s = grb & 127;
                bf16x4 v;
                #pragma unroll
                for (int r = 0; r < 4; ++r) v[r] = (__bf16)(acc[ri][j][r] + bv);
                *reinterpret_cast<bf16x4*>(&C[((size_t)b * DIM + gc) * SEQ + s]) = v;
            }
        }
    }
#undef TILE
#undef STAGE_A
#undef STAGE_B
#undef LDF
}

// ---------------- fused attention, LDS-pipelined ----------------
// 512 blocks (XCD-swizzled), 4 waves, 32 rows/block. 40KB LDS -> 4 blocks/CU.
// Phase 1: K[128][64]+Q[32][64] chunks double-buffered via global_load_lds;
// read-side XOR swizzle byte^=(row&7)<<4 with inverse-swizzled global source.
// Phase 2: V[64][128] chunks, same pattern; softmax arrays union the buffers.
__global__ __launch_bounds__(256) void attn_kernel(const __bf16* __restrict__ Q,
                                                   const __bf16* __restrict__ Km,
                                                   const __bf16* __restrict__ Vt,
                                                   __bf16* __restrict__ Ab) {
    __shared__ __align__(16) char smem[40960];
    float  (*Ssh)[132] = (float(*)[132])(smem);            // [32][132] f32, phase-1 out
    __bf16 (*Psh)[136] = (__bf16(*)[136])(smem + 16896);   // [32][136] bf16

    const int bid = blockIdx.x;
    const int logical = (bid & 7) * 64 + (bid >> 3);  // XCD x -> batches [16x,16x+16)
    const int b = logical >> 2, rt = logical & 3;
    const int tid = threadIdx.x, wave = tid >> 6, lane = tid & 63;
    const int lr = lane & 15, lk = (lane >> 4) * 8, rbase = (lane >> 4) * 4;
    const __bf16* Qb = Q  + ((size_t)b * SEQ + rt * 32) * DIM;
    const __bf16* Kb = Km + (size_t)b * SEQ * DIM;
    const __bf16* Vb = Vt + (size_t)b * DIM * SEQ;

    // staging source col pre-swizzle (128B rows): col=(lane&7)*16, row&7=(lane>>3)&7
    const int csrc = ((lane & 7) * 16) ^ (((lane >> 3) & 7) << 4);

    // ---- phase 1: S = Q K^T, chunks of BK=64 ----
    f32x4 acc[2][2] = {};
    {
        auto stage_kq = [&](int buf, int c) {
            char* Kd = smem + buf * 20480 + wave * 4096;
            char* Qd = smem + buf * 20480 + 16384 + wave * 1024;
            const char* Ks = (const char*)Kb + (size_t)(wave * 32 + (lane >> 3)) * 2048 + c * 128 + csrc;
            #pragma unroll
            for (int q = 0; q < 4; ++q)
                gload16(Ks + (size_t)q * 8 * 2048, Kd + q * 1024);
            const char* Qs = (const char*)Qb + (size_t)(wave * 8 + (lane >> 3)) * 2048 + c * 128 + csrc;
            gload16(Qs, Qd);
        };
        stage_kq(0, 0);
        WAITV(0);
        BARRIER();
        for (int c = 0; c < 16; ++c) {
            const int rb = c & 1;
            if (c < 15) stage_kq(rb ^ 1, c + 1);
            const char* Kl = smem + rb * 20480;
            const char* Ql = Kl + 16384;
            bf16x8 qf[2][2], kf[2][2];
            #pragma unroll
            for (int i = 0; i < 2; ++i)
                #pragma unroll
                for (int ks = 0; ks < 2; ++ks) {
                    const int r = i * 16 + lr;
                    qf[i][ks] = *reinterpret_cast<const bf16x8*>(
                        Ql + r * 128 + ((ks * 64 + (lane >> 4) * 16) ^ ((r & 7) << 4)));
                }
            #pragma unroll
            for (int j = 0; j < 2; ++j)
                #pragma unroll
                for (int ks = 0; ks < 2; ++ks) {
                    const int r = wave * 32 + j * 16 + lr;
                    kf[j][ks] = *reinterpret_cast<const bf16x8*>(
                        Kl + r * 128 + ((ks * 64 + (lane >> 4) * 16) ^ ((r & 7) << 4)));
                }
            __builtin_amdgcn_s_setprio(1);
            #pragma unroll
            for (int i = 0; i < 2; ++i)
                #pragma unroll
                for (int j = 0; j < 2; ++j)
                    #pragma unroll
                    for (int ks = 0; ks < 2; ++ks)
                        acc[i][j] = MFMA(qf[i][ks], kf[j][ks], acc[i][j]);
            __builtin_amdgcn_s_setprio(0);
            WAITV(0);
            BARRIER();
        }
    }
    const float scale = 0.03125f;  // 1/sqrt(1024)
    #pragma unroll
    for (int i = 0; i < 2; ++i)
        #pragma unroll
        for (int j = 0; j < 2; ++j)
            #pragma unroll
            for (int r = 0; r < 4; ++r)
                Ssh[i * 16 + rbase + r][wave * 32 + j * 16 + lr] = acc[i][j][r] * scale;
    __syncthreads();

    // ---- wave-parallel softmax: 8 threads/row, shfl_xor reduce ----
    {
        const int row = tid >> 3;
        const int c0  = (tid & 7) * 16;
        float4 v0 = *reinterpret_cast<const float4*>(&Ssh[row][c0]);
        float4 v1 = *reinterpret_cast<const float4*>(&Ssh[row][c0 + 4]);
        float4 v2 = *reinterpret_cast<const float4*>(&Ssh[row][c0 + 8]);
        float4 v3 = *reinterpret_cast<const float4*>(&Ssh[row][c0 + 12]);
        float e[16] = {v0.x, v0.y, v0.z, v0.w, v1.x, v1.y, v1.z, v1.w,
                       v2.x, v2.y, v2.z, v2.w, v3.x, v3.y, v3.z, v3.w};
        float mx = e[0];
        #pragma unroll
        for (int u = 1; u < 16; ++u) mx = fmaxf(mx, e[u]);
        mx = fmaxf(mx, __shfl_xor(mx, 1));
        mx = fmaxf(mx, __shfl_xor(mx, 2));
        mx = fmaxf(mx, __shfl_xor(mx, 4));
        float s = 0.f;
        #pragma unroll
        for (int u = 0; u < 16; ++u) { e[u] = __expf(e[u] - mx); s += e[u]; }
        s += __shfl_xor(s, 1);
        s += __shfl_xor(s, 2);
        s += __shfl_xor(s, 4);
        const float inv = 1.f / s;
        bf16x8 p0, p1;
        #pragma unroll
        for (int u = 0; u < 8; ++u) { p0[u] = (__bf16)(e[u] * inv); p1[u] = (__bf16)(e[u + 8] * inv); }
        *reinterpret_cast<bf16x8*>(&Psh[row][c0])     = p0;
        *reinterpret_cast<bf16x8*>(&Psh[row][c0 + 8]) = p1;
    }
    __syncthreads();

    // P-frags to regs; then sync so V staging may overwrite the Psh region
    bf16x8 pf[2][4];
    #pragma unroll
    for (int i = 0; i < 2; ++i)
        #pragma unroll
        for (int ks = 0; ks < 4; ++ks)
            pf[i][ks] = *reinterpret_cast<const bf16x8*>(&Psh[i * 16 + lr][ks * 32 + lk]);
    __syncthreads();   // drains lgkm: pf safe in regs before buffers reused

    // ---- phase 2: att = P V, V chunks [64 rows][128 s] double-buffered ----
    __bf16* Ao = Ab + ((size_t)b * SEQ + rt * 32) * DIM;
    {
        auto stage_v = [&](int buf, int c) {
            char* Vd = smem + buf * 16384 + wave * 4096;
            #pragma unroll
            for (int q = 0; q < 4; ++q) {
                const int rowl = wave * 16 + q * 4 + (lane >> 4);
                const char* Vs = (const char*)Vb + (size_t)(c * 64 + rowl) * 256 +
                                 (((lane & 15) * 16) ^ ((rowl & 7) << 4));
                gload16(Vs, Vd + q * 1024);
            }
        };
        stage_v(0, 0);
        WAITV(0);
        BARRIER();
        for (int c = 0; c < 16; ++c) {
            const int rb = c & 1;
            if (c < 15) stage_v(rb ^ 1, c + 1);
            const char* Vl = smem + rb * 16384;
            f32x4 a2[2] = {};
            const int r = wave * 16 + lr;
            #pragma unroll
            for (int ks = 0; ks < 4; ++ks) {
                bf16x8 vf = *reinterpret_cast<const bf16x8*>(
                    Vl + r * 256 + ((ks * 64 + (lane >> 4) * 16) ^ ((r & 7) << 4)));
                a2[0] = MFMA(pf[0][ks], vf, a2[0]);
                a2[1] = MFMA(pf[1][ks], vf, a2[1]);
            }
            const int n0 = c * 64 + wave * 16;
            #pragma unroll
            for (int i = 0; i < 2; ++i)
                #pragma unroll
                for (int rr = 0; rr < 4; ++rr)
                    Ao[(size_t)(i * 16 + rbase + rr) * DIM + n0 + lr] = (__bf16)a2[i][rr];
            WAITV(8);   // 8 newest = this iter's stores; staged loads retired
            BARRIER();
        }
    }
}

extern "C" void kernel_launch(void* const* d_in, const int* in_sizes, int n_in,
                              void* d_out, int out_size, void* d_ws, size_t ws_size,
                              hipStream_t stream) {
    const float* x  = (const float*)d_in[0];
    const float* Wq = (const float*)d_in[1];
    const float* bq = (const float*)d_in[2];
    const float* Wk = (const float*)d_in[3];
    const float* bk = (const float*)d_in[4];
    const float* Wv = (const float*)d_in[5];
    const float* bv = (const float*)d_in[6];
    const float* Wo = (const float*)d_in[7];
    const float* bo = (const float*)d_in[8];

    char* ws = (char*)d_ws;
    const size_t MB = 1024 * 1024;
    __bf16* Xb  = (__bf16*)(ws);              // 32MB; reused as Ab after attention
    __bf16* Wqb = (__bf16*)(ws + 32 * MB);    // 2MB each
    __bf16* Wkb = (__bf16*)(ws + 34 * MB);
    __bf16* Wvb = (__bf16*)(ws + 36 * MB);
    __bf16* Wob = (__bf16*)(ws + 38 * MB);
    __bf16* Qb  = (__bf16*)(ws + 40 * MB);    // 32MB
    __bf16* Kb  = (__bf16*)(ws + 72 * MB);    // 32MB
    __bf16* Vt  = (__bf16*)(ws + 104 * MB);   // 32MB
    __bf16* Ab  = Xb;

    const int nX = MTOT * DIM;
    const int nW = DIM * DIM;
    cast_f32_bf16<<<nX / 8 / 256, 256, 0, stream>>>(x, Xb, nX);
    cast_f32_bf16<<<nW / 8 / 256, 256, 0, stream>>>(Wq, Wqb, nW);
    cast_f32_bf16<<<nW / 8 / 256, 256, 0, stream>>>(Wk, Wkb, nW);
    cast_f32_bf16<<<nW / 8 / 256, 256, 0, stream>>>(Wv, Wvb, nW);
    cast_f32_bf16<<<nW / 8 / 256, 256, 0, stream>>>(Wo, Wob, nW);

    gemm256<0><<<256, 512, 0, stream>>>(Xb, Wqb, bq, (void*)Qb);
    gemm256<0><<<256, 512, 0, stream>>>(Xb, Wkb, bk, (void*)Kb);
    gemm256<2><<<256, 512, 0, stream>>>(Xb, Wvb, bv, (void*)Vt);

    attn_kernel<<<512, 256, 0, stream>>>(Qb, Kb, Vt, Ab);

    gemm256<1><<<256, 512, 0, stream>>>(Ab, Wob, bo, d_out);
}